// Round 5
// baseline (1386.163 us; speedup 1.0000x reference)
//
#include <hip/hip_runtime.h>
#include <math.h>

// Problem dims
#define CDIM 2048
#define NMEM 200
#define BATCH 64
#define HWLEN 196
#define NCLS 200
#define K3 6144            // CDIM*3

// ---------------------------------------------------------------------------
// Kernel A: k1[n, o*3+kk] = relu( sum_i mem_feat[n,i]*wt[i, o*3+kk] + bt[o] )
// GEMM M=200, N=6144, K=2048.  BM=64 BN=64 BK=16, 256 thr, 4x4 microtile.
// ---------------------------------------------------------------------------
__global__ __launch_bounds__(256) void gemm1_kernel(
    const float* __restrict__ A,      // [200,2048]
    const float* __restrict__ Bw,     // [2048,6144]
    const float* __restrict__ bt,     // [2048]
    float* __restrict__ Cout)         // [200,6144]
{
    __shared__ float As[16 * 68];   // [k][m], stride 68 (pad: conflicts + f4 align)
    __shared__ float Bs[16 * 64];   // [k][n]
    const int n0 = blockIdx.x * 64;
    const int m0 = blockIdx.y * 64;
    const int t  = threadIdx.x;
    const int tx = t & 15;          // 16 cols of 4
    const int ty = t >> 4;          // 16 rows of 4

    float acc[4][4] = {};

    for (int k0 = 0; k0 < 2048; k0 += 16) {
        // stage A tile (64 rows x 16 k) -> As[k][m]
        #pragma unroll
        for (int it = 0; it < 4; ++it) {
            int l  = t + it * 256;
            int ml = l >> 4, kl = l & 15;
            int row = m0 + ml;
            float v = (row < NMEM) ? A[row * 2048 + k0 + kl] : 0.f;
            As[kl * 68 + ml] = v;
        }
        // stage B tile (16 k x 64 n) -> Bs[k][n]
        #pragma unroll
        for (int it = 0; it < 4; ++it) {
            int l  = t + it * 256;
            int kl = l >> 6, nl = l & 63;
            Bs[kl * 64 + nl] = Bw[(size_t)(k0 + kl) * K3 + n0 + nl];
        }
        __syncthreads();

        const float4* As4 = (const float4*)As;
        const float4* Bs4 = (const float4*)Bs;
        #pragma unroll
        for (int k = 0; k < 16; ++k) {
            float4 a = As4[k * 17 + ty];
            float4 b = Bs4[k * 16 + tx];
            float av[4] = {a.x, a.y, a.z, a.w};
            float bv[4] = {b.x, b.y, b.z, b.w};
            #pragma unroll
            for (int jm = 0; jm < 4; ++jm)
                #pragma unroll
                for (int jn = 0; jn < 4; ++jn)
                    acc[jm][jn] += av[jm] * bv[jn];
        }
        __syncthreads();
    }

    #pragma unroll
    for (int jm = 0; jm < 4; ++jm) {
        int row = m0 + ty * 4 + jm;
        if (row < NMEM) {
            int colbase = n0 + tx * 4;
            float4 o;
            float* op = (float*)&o;
            #pragma unroll
            for (int jn = 0; jn < 4; ++jn) {
                int col = colbase + jn;
                float v = acc[jm][jn] + bt[col / 3];
                op[jn] = v > 0.f ? v : 0.f;
            }
            *(float4*)(&Cout[(size_t)row * K3 + colbase]) = o;
        }
    }
}

// ---------------------------------------------------------------------------
// Kernel B: 3-tap conv as GEMM over i.
// k2[n,o,p] = relu( bc[o] + sum_i { p=0: a0*w1+a1*w2 ; p=1: a0*w0+a1*w1+a2*w2 ;
//                                   p=2: a1*w0+a2*w1 } ),  a=k1[n,i,*], w=wc[o,i,*]
// BM=64 (n) BN=16 (o) BK=16 (i), 256 thr, microtile 2n x 2o x 3p.
// ---------------------------------------------------------------------------
__global__ __launch_bounds__(256) void gemm2_conv_kernel(
    const float* __restrict__ k1,   // [200, 6144] = [n][i*3+pp]
    const float* __restrict__ wc,   // [2048, 6144] = [o][i*3+kk]
    const float* __restrict__ bc,   // [2048]
    float* __restrict__ k2)         // [200, 6144] = [n][o*3+p]
{
    __shared__ float As[16 * 64 * 4];   // [i][n][4] (pad kk->4 for f4 align)
    __shared__ float Bs[16 * 16 * 4];   // [i][o][4]
    const int o0 = blockIdx.x * 16;
    const int m0 = blockIdx.y * 64;
    const int t  = threadIdx.x;
    const int tx = t & 7;    // 8  -> 2 o each
    const int ty = t >> 3;   // 32 -> 2 n each

    // k0-invariant staging decompositions (static-indexed register arrays)
    int a_lds[12], a_goff[12], a_ok[12];
    #pragma unroll
    for (int it = 0; it < 12; ++it) {
        int l  = t + it * 256;           // 0..3071 over 64n x 16i x 3pp
        int nl = l / 48; int r = l - nl * 48;
        int il = r / 3;  int pp = r - il * 3;
        a_lds[it]  = (il * 64 + nl) * 4 + pp;
        int row = m0 + nl;
        a_ok[it]   = row < NMEM;
        a_goff[it] = (row < NMEM ? row : 0) * K3 + il * 3 + pp;
    }
    int b_lds[3], b_goff[3];
    #pragma unroll
    for (int it = 0; it < 3; ++it) {
        int l  = t + it * 256;           // 0..767 over 16o x 16i x 3kk
        int ol = l / 48; int r = l - ol * 48;
        int il = r / 3;  int kk = r - il * 3;
        b_lds[it]  = (il * 16 + ol) * 4 + kk;
        b_goff[it] = (o0 + ol) * K3 + il * 3 + kk;
    }

    float acc[3][2][2] = {};

    for (int k0 = 0; k0 < 2048; k0 += 16) {
        const int koff = k0 * 3;
        #pragma unroll
        for (int it = 0; it < 12; ++it) {
            float v = a_ok[it] ? k1[a_goff[it] + koff] : 0.f;
            As[a_lds[it]] = v;
        }
        #pragma unroll
        for (int it = 0; it < 3; ++it)
            Bs[b_lds[it]] = wc[b_goff[it] + koff];
        __syncthreads();

        const float4* As4 = (const float4*)As;
        const float4* Bs4 = (const float4*)Bs;
        #pragma unroll
        for (int i = 0; i < 16; ++i) {
            float4 a0 = As4[i * 64 + ty * 2 + 0];
            float4 a1 = As4[i * 64 + ty * 2 + 1];
            float4 w0 = Bs4[i * 16 + tx * 2 + 0];
            float4 w1 = Bs4[i * 16 + tx * 2 + 1];
            #pragma unroll
            for (int jn = 0; jn < 2; ++jn) {
                float4 a = jn ? a1 : a0;
                #pragma unroll
                for (int jo = 0; jo < 2; ++jo) {
                    float4 w = jo ? w1 : w0;
                    acc[0][jn][jo] += a.x * w.y + a.y * w.z;
                    acc[1][jn][jo] += a.x * w.x + a.y * w.y + a.z * w.z;
                    acc[2][jn][jo] += a.y * w.x + a.z * w.y;
                }
            }
        }
        __syncthreads();
    }

    #pragma unroll
    for (int jn = 0; jn < 2; ++jn) {
        int row = m0 + ty * 2 + jn;
        if (row < NMEM) {
            #pragma unroll
            for (int jo = 0; jo < 2; ++jo) {
                int o = o0 + tx * 2 + jo;
                float bias = bc[o];
                size_t base = (size_t)row * K3 + o * 3;
                #pragma unroll
                for (int p = 0; p < 3; ++p) {
                    float v = acc[p][jn][jo] + bias;
                    k2[base + p] = v > 0.f ? v : 0.f;
                }
            }
        }
    }
}

// ---------------------------------------------------------------------------
// Kernel C: g[b,c,kk] = sum_t feat[b,c,t] * w_sp[t-kk+1]  (valid range)
// One wave per (b,c) row; 4 waves/block.
// ---------------------------------------------------------------------------
__global__ __launch_bounds__(256) void gfeat_kernel(
    const float* __restrict__ feat,   // [64*2048, 196]
    const float* __restrict__ w_sp,   // [196]
    float* __restrict__ g)            // [64*2048, 3]
{
    __shared__ float ws[196];
    const int t = threadIdx.x;
    if (t < 196) ws[t] = w_sp[t];
    __syncthreads();

    const int wave = t >> 6, lane = t & 63;
    const int row  = blockIdx.x * 4 + wave;   // < 131072
    const float* f = feat + (size_t)row * HWLEN;

    float a0 = 0.f, a1 = 0.f, a2 = 0.f;
    for (int s = lane; s < HWLEN; s += 64) {
        float v = f[s];
        a1 += v * ws[s];
        if (s < HWLEN - 1) a0 += v * ws[s + 1];
        if (s >= 1)        a2 += v * ws[s - 1];
    }
    #pragma unroll
    for (int off = 32; off; off >>= 1) {
        a0 += __shfl_down(a0, off, 64);
        a1 += __shfl_down(a1, off, 64);
        a2 += __shfl_down(a2, off, 64);
    }
    if (lane == 0) {
        float* gp = g + (size_t)row * 3;
        gp[0] = a0; gp[1] = a1; gp[2] = a2;
    }
}

// ---------------------------------------------------------------------------
// Kernel D: cls[b,n] = b_sp + sum_j g[b,j] * k2[n,j]   (j over 6144)
// One block per n; k2 row staged in LDS.
// ---------------------------------------------------------------------------
__global__ __launch_bounds__(256) void clsfeat_kernel(
    const float* __restrict__ g,      // [64, 6144]
    const float* __restrict__ k2,     // [200, 6144]
    const float* __restrict__ b_sp,   // [1]
    float* __restrict__ cls)          // [64, 200]
{
    __shared__ float krow[K3];
    __shared__ float partial[4];
    const int n = blockIdx.x;
    const int t = threadIdx.x;
    for (int j = t; j < K3; j += 256) krow[j] = k2[(size_t)n * K3 + j];
    __syncthreads();
    const float bsp = b_sp[0];

    for (int b = 0; b < BATCH; ++b) {
        float acc = 0.f;
        const float* gb = g + (size_t)b * K3;
        for (int j = t; j < K3; j += 256) acc += gb[j] * krow[j];
        #pragma unroll
        for (int off = 32; off; off >>= 1) acc += __shfl_down(acc, off, 64);
        if ((t & 63) == 0) partial[t >> 6] = acc;
        __syncthreads();
        if (t == 0)
            cls[b * NCLS + n] = partial[0] + partial[1] + partial[2] + partial[3] + bsp;
        __syncthreads();
    }
}

// ---------------------------------------------------------------------------
// Kernel E: CosFace.  out[b,n] = 30*( dot(xn_b, wn_n) - 0.5*[label_b==n] )
// One block per b.
// ---------------------------------------------------------------------------
__global__ __launch_bounds__(256) void cosface_kernel(
    const float* __restrict__ cls,    // [64, 200]
    const float* __restrict__ w_cls,  // [200, 200]
    const int* __restrict__ label,    // [64]
    float* __restrict__ out)          // [64, 200]
{
    __shared__ float row[NCLS];
    __shared__ float part[4];
    const int b = blockIdx.x, t = threadIdx.x;

    float v = (t < NCLS) ? cls[b * NCLS + t] : 0.f;
    if (t < NCLS) row[t] = v;
    float ss = v * v;
    #pragma unroll
    for (int off = 32; off; off >>= 1) ss += __shfl_down(ss, off, 64);
    if ((t & 63) == 0) part[t >> 6] = ss;
    __syncthreads();

    const float xn = sqrtf(part[0] + part[1] + part[2] + part[3]);
    const int lab = label[b];
    if (t < NCLS) {
        float dot = 0.f, wn = 0.f;
        const float* w = w_cls + t * NCLS;
        for (int j = 0; j < NCLS; ++j) {
            float wv = w[j];
            dot += row[j] * wv;
            wn  += wv * wv;
        }
        float cosv = dot / (xn * sqrtf(wn));
        out[b * NCLS + t] = 30.0f * (cosv - (t == lab ? 0.5f : 0.0f));
    }
}

// ---------------------------------------------------------------------------
extern "C" void kernel_launch(void* const* d_in, const int* in_sizes, int n_in,
                              void* d_out, int out_size, void* d_ws, size_t ws_size,
                              hipStream_t stream) {
    const float* feat     = (const float*)d_in[0];
    const int*   label    = (const int*)  d_in[1];
    const float* mem_feat = (const float*)d_in[2];
    const float* wt       = (const float*)d_in[3];
    const float* bt       = (const float*)d_in[4];
    const float* wc       = (const float*)d_in[5];
    const float* bc       = (const float*)d_in[6];
    const float* w_sp     = (const float*)d_in[7];
    const float* b_sp     = (const float*)d_in[8];
    const float* w_cls    = (const float*)d_in[9];
    float* out = (float*)d_out;

    float* ws  = (float*)d_ws;
    float* k1  = ws;                    // 200*6144
    float* k2  = k1 + NMEM * K3;        // 200*6144
    float* g   = k2 + NMEM * K3;        // 64*6144
    float* cls = g + BATCH * K3;        // 64*200

    gemm1_kernel<<<dim3(96, 4), 256, 0, stream>>>(mem_feat, wt, bt, k1);
    gemm2_conv_kernel<<<dim3(128, 4), 256, 0, stream>>>(k1, wc, bc, k2);
    gfeat_kernel<<<BATCH * CDIM / 4, 256, 0, stream>>>(feat, w_sp, g);
    clsfeat_kernel<<<NCLS, 256, 0, stream>>>(g, k2, b_sp, cls);
    cosface_kernel<<<BATCH, 256, 0, stream>>>(cls, w_cls, label, out);
}

// Round 10
// 461.103 us; speedup vs baseline: 3.0062x; 3.0062x over previous
//
#include <hip/hip_runtime.h>
#include <math.h>

// Problem dims
#define CDIM 2048
#define NMEM 200
#define BATCH 64
#define HWLEN 196
#define NCLS 200
#define K3 6144            // CDIM*3

using bf16x8 = __attribute__((ext_vector_type(8))) __bf16;
using f32x4  = __attribute__((ext_vector_type(4))) float;

#define GAS __attribute__((address_space(1)))
#define LAS __attribute__((address_space(3)))

__device__ __forceinline__ void gload16(const void* g, void* l) {
    __builtin_amdgcn_global_load_lds((const GAS void*)g, (LAS void*)l, 16, 0, 0);
}

__device__ __forceinline__ unsigned short f2bf(float f) {
    unsigned u = __builtin_bit_cast(unsigned, f);
    unsigned r = u + 0x7FFFu + ((u >> 16) & 1u);   // RNE
    return (unsigned short)(r >> 16);
}

// ===========================================================================
// MFMA path (used when ws_size is large enough)
// ===========================================================================

// --- prep: mem_feat f32 -> bf16 [200][2048] ---
__global__ __launch_bounds__(256) void cvt_mem_kernel(
    const float* __restrict__ mf, unsigned short* __restrict__ outp)
{
    const int n = blockIdx.x, t = threadIdx.x;
    #pragma unroll
    for (int k = 0; k < 8; ++k) {
        int i = t + k * 256;
        outp[n * 2048 + i] = f2bf(mf[n * 2048 + i]);
    }
}

// --- prep: wtT[col][i] = bf16(wt[i][col]), 64x64 LDS-tiled transpose ---
__global__ __launch_bounds__(256) void transpose_wt_kernel(
    const float* __restrict__ wt,      // [2048][6144]
    unsigned short* __restrict__ wtT)  // [6144][2048] bf16
{
    __shared__ float tile[64 * 65];
    const int i0 = blockIdx.x * 64;    // 32 blocks
    const int c0 = blockIdx.y * 64;    // 96 blocks
    const int t  = threadIdx.x;
    #pragma unroll
    for (int rr = 0; rr < 16; ++rr) {
        int idx = rr * 256 + t;
        int il = idx >> 6, cl = idx & 63;
        tile[cl * 65 + il] = wt[(long)(i0 + il) * K3 + c0 + cl];
    }
    __syncthreads();
    #pragma unroll
    for (int rr = 0; rr < 16; ++rr) {
        int idx = rr * 256 + t;
        int cl = idx >> 6, il = idx & 63;
        wtT[(long)(c0 + cl) * 2048 + i0 + il] = f2bf(tile[cl * 65 + il]);
    }
}

// --- prep: Bbig[o*3+p][j] = bf16( wc[o][j+1-p] * mask_p(j%3) ) ---
// mask: p=0 -> j%3 in {0,1}; p=1 -> all; p=2 -> j%3 in {1,2}.
// Masked entries exactly cover the shift's OOB cells (verified vs round-5 taps).
__global__ __launch_bounds__(256) void prep_bbig_kernel(
    const float* __restrict__ wc,       // [2048][6144]
    unsigned short* __restrict__ Bbig)  // [6144][6144] bf16
{
    __shared__ float row[K3];
    const int o = blockIdx.x, t = threadIdx.x;
    for (int j = t; j < K3; j += 256) row[j] = wc[(long)o * K3 + j];
    __syncthreads();
    #pragma unroll
    for (int p = 0; p < 3; ++p) {
        unsigned short* dst = Bbig + (long)(o * 3 + p) * K3;
        for (int j = t; j < K3; j += 256) {
            int q = j - (j / 3) * 3;
            bool valid = (p == 1) || (p == 0 && q < 2) || (p == 2 && q > 0);
            dst[j] = f2bf(valid ? row[j + 1 - p] : 0.f);
        }
    }
}

// --- MFMA GEMM: C[m, col] = relu( sum_k A[m,k]*B[col,k] + bias[col/3] )
// M=200 (grid pads to 224), N=6144, K=KDIM. BM=32 BN=128 BK=64, 4 waves.
// LDS [rows][64k] bf16, XOR swizzle group ^= (row&7) on 16B groups (T2);
// linear LDS dest + pre-swizzled global source + swizzled read (rule #21).
template<int KDIM, bool OUTBF>
__global__ __launch_bounds__(256) void mfma_gemm_kernel(
    const unsigned short* __restrict__ A,   // [200][KDIM] bf16 bits
    const unsigned short* __restrict__ B,   // [6144][KDIM] bf16 bits
    const float* __restrict__ bias,         // [2048]
    void* __restrict__ Cout)                // [200][6144] bf16 or f32
{
    __shared__ unsigned short As[32 * 64];   // 4 KB
    __shared__ unsigned short Bs[128 * 64];  // 16 KB
    const int t = threadIdx.x;
    const int lane = t & 63, wv = t >> 6;
    const int n0 = blockIdx.x * 128;
    const int m0 = blockIdx.y * 32;

    // staging addresses (k0-invariant)
    const int srow = lane >> 3;              // 0..7
    const int sgg  = lane & 7;
    const int a_r  = wv * 8 + srow;          // 0..31
    const int a_row_g = (m0 + a_r < NMEM) ? (m0 + a_r) : (NMEM - 1);
    const long a_off = (long)a_row_g * KDIM + (sgg ^ (a_r & 7)) * 8;

    long b_off[4];
    #pragma unroll
    for (int rr = 0; rr < 4; ++rr) {
        int chunk = rr * 4 + wv;             // 0..15
        int c = chunk * 8 + srow;            // 0..127
        b_off[rr] = (long)(n0 + c) * KDIM + (sgg ^ (c & 7)) * 8;
    }

    f32x4 zero = {0.f, 0.f, 0.f, 0.f};
    f32x4 acc[2][2];
    acc[0][0] = zero; acc[0][1] = zero; acc[1][0] = zero; acc[1][1] = zero;

    for (int k0 = 0; k0 < KDIM; k0 += 64) {
        gload16(A + a_off + k0, (char*)As + wv * 1024);
        #pragma unroll
        for (int rr = 0; rr < 4; ++rr)
            gload16(B + b_off[rr] + k0, (char*)Bs + (rr * 4 + wv) * 1024);
        __syncthreads();   // compiler drains vmcnt before s_barrier (m97 pattern)

        #pragma unroll
        for (int s = 0; s < 2; ++s) {
            bf16x8 af[2], bfr[2];
            #pragma unroll
            for (int m = 0; m < 2; ++m) {
                int r = m * 16 + (lane & 15);
                int g = (s * 4 + (lane >> 4)) ^ (r & 7);
                af[m] = *(const bf16x8*)((const char*)As + r * 128 + g * 16);
            }
            #pragma unroll
            for (int n = 0; n < 2; ++n) {
                int c = wv * 32 + n * 16 + (lane & 15);
                int g = (s * 4 + (lane >> 4)) ^ (c & 7);
                bfr[n] = *(const bf16x8*)((const char*)Bs + c * 128 + g * 16);
            }
            #pragma unroll
            for (int m = 0; m < 2; ++m)
                #pragma unroll
                for (int n = 0; n < 2; ++n)
                    acc[m][n] = __builtin_amdgcn_mfma_f32_16x16x32_bf16(
                        af[m], bfr[n], acc[m][n], 0, 0, 0);
        }
        __syncthreads();
    }

    // epilogue: C/D layout col=lane&15, row=(lane>>4)*4+reg (m89-verified)
    const int col_b = n0 + wv * 32 + (lane & 15);
    #pragma unroll
    for (int m = 0; m < 2; ++m) {
        int row_b = m0 + m * 16 + (lane >> 4) * 4;
        #pragma unroll
        for (int r = 0; r < 4; ++r) {
            int row = row_b + r;
            if (row < NMEM) {
                #pragma unroll
                for (int n = 0; n < 2; ++n) {
                    int col = col_b + n * 16;
                    float v = acc[m][n][r] + bias[col / 3];
                    v = v > 0.f ? v : 0.f;
                    if (OUTBF)
                        ((unsigned short*)Cout)[(long)row * K3 + col] = f2bf(v);
                    else
                        ((float*)Cout)[(long)row * K3 + col] = v;
                }
            }
        }
    }
}

// ===========================================================================
// Legacy f32 path (verified round 5) — fallback if ws too small
// ===========================================================================

__global__ __launch_bounds__(256) void gemm1_kernel(
    const float* __restrict__ A, const float* __restrict__ Bw,
    const float* __restrict__ bt, float* __restrict__ Cout)
{
    __shared__ float As[16 * 68];
    __shared__ float Bs[16 * 64];
    const int n0 = blockIdx.x * 64, m0 = blockIdx.y * 64;
    const int t = threadIdx.x, tx = t & 15, ty = t >> 4;
    float acc[4][4] = {};
    for (int k0 = 0; k0 < 2048; k0 += 16) {
        #pragma unroll
        for (int it = 0; it < 4; ++it) {
            int l = t + it * 256, ml = l >> 4, kl = l & 15, row = m0 + ml;
            As[kl * 68 + ml] = (row < NMEM) ? A[row * 2048 + k0 + kl] : 0.f;
        }
        #pragma unroll
        for (int it = 0; it < 4; ++it) {
            int l = t + it * 256, kl = l >> 6, nl = l & 63;
            Bs[kl * 64 + nl] = Bw[(size_t)(k0 + kl) * K3 + n0 + nl];
        }
        __syncthreads();
        const float4* As4 = (const float4*)As;
        const float4* Bs4 = (const float4*)Bs;
        #pragma unroll
        for (int k = 0; k < 16; ++k) {
            float4 a = As4[k * 17 + ty];
            float4 b = Bs4[k * 16 + tx];
            float av[4] = {a.x, a.y, a.z, a.w};
            float bv[4] = {b.x, b.y, b.z, b.w};
            #pragma unroll
            for (int jm = 0; jm < 4; ++jm)
                #pragma unroll
                for (int jn = 0; jn < 4; ++jn)
                    acc[jm][jn] += av[jm] * bv[jn];
        }
        __syncthreads();
    }
    #pragma unroll
    for (int jm = 0; jm < 4; ++jm) {
        int row = m0 + ty * 4 + jm;
        if (row < NMEM) {
            int colbase = n0 + tx * 4;
            float4 o; float* op = (float*)&o;
            #pragma unroll
            for (int jn = 0; jn < 4; ++jn) {
                float v = acc[jm][jn] + bt[(colbase + jn) / 3];
                op[jn] = v > 0.f ? v : 0.f;
            }
            *(float4*)(&Cout[(size_t)row * K3 + colbase]) = o;
        }
    }
}

__global__ __launch_bounds__(256) void gemm2_conv_kernel(
    const float* __restrict__ k1, const float* __restrict__ wc,
    const float* __restrict__ bc, float* __restrict__ k2)
{
    __shared__ float As[16 * 64 * 4];
    __shared__ float Bs[16 * 16 * 4];
    const int o0 = blockIdx.x * 16, m0 = blockIdx.y * 64;
    const int t = threadIdx.x, tx = t & 7, ty = t >> 3;
    int a_lds[12], a_goff[12], a_ok[12];
    #pragma unroll
    for (int it = 0; it < 12; ++it) {
        int l = t + it * 256;
        int nl = l / 48, r = l - nl * 48, il = r / 3, pp = r - il * 3;
        a_lds[it] = (il * 64 + nl) * 4 + pp;
        int row = m0 + nl;
        a_ok[it] = row < NMEM;
        a_goff[it] = (row < NMEM ? row : 0) * K3 + il * 3 + pp;
    }
    int b_lds[3], b_goff[3];
    #pragma unroll
    for (int it = 0; it < 3; ++it) {
        int l = t + it * 256;
        int ol = l / 48, r = l - ol * 48, il = r / 3, kk = r - il * 3;
        b_lds[it] = (il * 16 + ol) * 4 + kk;
        b_goff[it] = (o0 + ol) * K3 + il * 3 + kk;
    }
    float acc[3][2][2] = {};
    for (int k0 = 0; k0 < 2048; k0 += 16) {
        const int koff = k0 * 3;
        #pragma unroll
        for (int it = 0; it < 12; ++it)
            As[a_lds[it]] = a_ok[it] ? k1[a_goff[it] + koff] : 0.f;
        #pragma unroll
        for (int it = 0; it < 3; ++it)
            Bs[b_lds[it]] = wc[b_goff[it] + koff];
        __syncthreads();
        const float4* As4 = (const float4*)As;
        const float4* Bs4 = (const float4*)Bs;
        #pragma unroll
        for (int i = 0; i < 16; ++i) {
            float4 a0 = As4[i * 64 + ty * 2 + 0];
            float4 a1 = As4[i * 64 + ty * 2 + 1];
            float4 w0 = Bs4[i * 16 + tx * 2 + 0];
            float4 w1 = Bs4[i * 16 + tx * 2 + 1];
            #pragma unroll
            for (int jn = 0; jn < 2; ++jn) {
                float4 a = jn ? a1 : a0;
                #pragma unroll
                for (int jo = 0; jo < 2; ++jo) {
                    float4 w = jo ? w1 : w0;
                    acc[0][jn][jo] += a.x * w.y + a.y * w.z;
                    acc[1][jn][jo] += a.x * w.x + a.y * w.y + a.z * w.z;
                    acc[2][jn][jo] += a.y * w.x + a.z * w.y;
                }
            }
        }
        __syncthreads();
    }
    #pragma unroll
    for (int jn = 0; jn < 2; ++jn) {
        int row = m0 + ty * 2 + jn;
        if (row < NMEM) {
            #pragma unroll
            for (int jo = 0; jo < 2; ++jo) {
                int o = o0 + tx * 2 + jo;
                float bb = bc[o];
                size_t base = (size_t)row * K3 + o * 3;
                #pragma unroll
                for (int p = 0; p < 3; ++p) {
                    float v = acc[p][jn][jo] + bb;
                    k2[base + p] = v > 0.f ? v : 0.f;
                }
            }
        }
    }
}

// ===========================================================================
// Shared tail kernels (verified round 5)
// ===========================================================================

__global__ __launch_bounds__(256) void gfeat_kernel(
    const float* __restrict__ feat, const float* __restrict__ w_sp,
    float* __restrict__ g)
{
    __shared__ float wsm[196];
    const int t = threadIdx.x;
    if (t < 196) wsm[t] = w_sp[t];
    __syncthreads();
    const int wave = t >> 6, lane = t & 63;
    const int row = blockIdx.x * 4 + wave;
    const float* f = feat + (size_t)row * HWLEN;
    float a0 = 0.f, a1 = 0.f, a2 = 0.f;
    for (int s = lane; s < HWLEN; s += 64) {
        float v = f[s];
        a1 += v * wsm[s];
        if (s < HWLEN - 1) a0 += v * wsm[s + 1];
        if (s >= 1)        a2 += v * wsm[s - 1];
    }
    #pragma unroll
    for (int off = 32; off; off >>= 1) {
        a0 += __shfl_down(a0, off, 64);
        a1 += __shfl_down(a1, off, 64);
        a2 += __shfl_down(a2, off, 64);
    }
    if (lane == 0) {
        float* gp = g + (size_t)row * 3;
        gp[0] = a0; gp[1] = a1; gp[2] = a2;
    }
}

__global__ __launch_bounds__(256) void clsfeat_kernel(
    const float* __restrict__ g, const float* __restrict__ k2,
    const float* __restrict__ b_sp, float* __restrict__ cls)
{
    __shared__ float krow[K3];
    __shared__ float partial[4];
    const int n = blockIdx.x, t = threadIdx.x;
    for (int j = t; j < K3; j += 256) krow[j] = k2[(size_t)n * K3 + j];
    __syncthreads();
    const float bsp = b_sp[0];
    for (int b = 0; b < BATCH; ++b) {
        float acc = 0.f;
        const float* gb = g + (size_t)b * K3;
        for (int j = t; j < K3; j += 256) acc += gb[j] * krow[j];
        #pragma unroll
        for (int off = 32; off; off >>= 1) acc += __shfl_down(acc, off, 64);
        if ((t & 63) == 0) partial[t >> 6] = acc;
        __syncthreads();
        if (t == 0)
            cls[b * NCLS + n] = partial[0] + partial[1] + partial[2] + partial[3] + bsp;
        __syncthreads();
    }
}

__global__ __launch_bounds__(256) void cosface_kernel(
    const float* __restrict__ cls, const float* __restrict__ w_cls,
    const int* __restrict__ label, float* __restrict__ out)
{
    __shared__ float row[NCLS];
    __shared__ float part[4];
    const int b = blockIdx.x, t = threadIdx.x;
    float v = (t < NCLS) ? cls[b * NCLS + t] : 0.f;
    if (t < NCLS) row[t] = v;
    float ss = v * v;
    #pragma unroll
    for (int off = 32; off; off >>= 1) ss += __shfl_down(ss, off, 64);
    if ((t & 63) == 0) part[t >> 6] = ss;
    __syncthreads();
    const float xn = sqrtf(part[0] + part[1] + part[2] + part[3]);
    const int lab = label[b];
    if (t < NCLS) {
        float dot = 0.f, wn = 0.f;
        const float* w = w_cls + t * NCLS;
        for (int j = 0; j < NCLS; ++j) {
            float wv = w[j];
            dot += row[j] * wv;
            wn  += wv * wv;
        }
        float cosv = dot / (xn * sqrtf(wn));
        out[b * NCLS + t] = 30.0f * (cosv - (t == lab ? 0.5f : 0.0f));
    }
}

// ===========================================================================
extern "C" void kernel_launch(void* const* d_in, const int* in_sizes, int n_in,
                              void* d_out, int out_size, void* d_ws, size_t ws_size,
                              hipStream_t stream) {
    const float* feat     = (const float*)d_in[0];
    const int*   label    = (const int*)  d_in[1];
    const float* mem_feat = (const float*)d_in[2];
    const float* wt       = (const float*)d_in[3];
    const float* bt       = (const float*)d_in[4];
    const float* wc       = (const float*)d_in[5];
    const float* bc       = (const float*)d_in[6];
    const float* w_sp     = (const float*)d_in[7];
    const float* b_sp     = (const float*)d_in[8];
    const float* w_cls    = (const float*)d_in[9];
    float* out = (float*)d_out;

    // MFMA-path workspace layout. wtT and bbig share one region: wtT is dead
    // after gemm1 (same-stream serialization), and prep_bbig runs after gemm1,
    // so bbig may overwrite it. NEED = 9.8 MB + 75.5 MB ≈ 85.3 MB.
    const size_t sz_k2   = (size_t)NMEM * K3 * 4;       // 4,915,200
    const size_t sz_g    = (size_t)BATCH * K3 * 4;      // 1,572,864
    const size_t sz_cls  = (size_t)BATCH * NCLS * 4;    //    51,200
    const size_t sz_memb = (size_t)NMEM * 2048 * 2;     //   819,200
    const size_t sz_k1b  = (size_t)NMEM * K3 * 2;       // 2,457,600
    const size_t sz_wtT  = (size_t)K3 * 2048 * 2;       // 25,165,824
    const size_t sz_bbig = (size_t)K3 * K3 * 2;         // 75,497,472
    const size_t sz_shared = (sz_bbig > sz_wtT) ? sz_bbig : sz_wtT;
    const size_t NEED = sz_k2 + sz_g + sz_cls + sz_memb + sz_k1b + sz_shared;

    if (ws_size >= NEED) {
        char* w = (char*)d_ws;
        float* k2            = (float*)w;           w += sz_k2;
        float* g             = (float*)w;           w += sz_g;
        float* cls           = (float*)w;           w += sz_cls;
        unsigned short* memb = (unsigned short*)w;  w += sz_memb;
        unsigned short* k1b  = (unsigned short*)w;  w += sz_k1b;
        unsigned short* wtT  = (unsigned short*)w;  // shared region
        unsigned short* bbig = (unsigned short*)w;  // aliases wtT (disjoint lifetime)

        cvt_mem_kernel<<<NMEM, 256, 0, stream>>>(mem_feat, memb);
        transpose_wt_kernel<<<dim3(32, 96), 256, 0, stream>>>(wt, wtT);
        mfma_gemm_kernel<2048, true><<<dim3(48, 7), 256, 0, stream>>>(memb, wtT, bt, k1b);
        // wtT dead from here; prep_bbig overwrites the shared region
        prep_bbig_kernel<<<CDIM, 256, 0, stream>>>(wc, bbig);
        mfma_gemm_kernel<K3, false><<<dim3(48, 7), 256, 0, stream>>>(k1b, bbig, bc, k2);
        gfeat_kernel<<<BATCH * CDIM / 4, 256, 0, stream>>>(feat, w_sp, g);
        clsfeat_kernel<<<NCLS, 256, 0, stream>>>(g, k2, b_sp, cls);
        cosface_kernel<<<BATCH, 256, 0, stream>>>(cls, w_cls, label, out);
    } else {
        // legacy f32 path (verified)
        float* ws  = (float*)d_ws;
        float* k1  = ws;
        float* k2  = k1 + NMEM * K3;
        float* g   = k2 + NMEM * K3;
        float* cls = g + BATCH * K3;

        gemm1_kernel<<<dim3(96, 4), 256, 0, stream>>>(mem_feat, wt, bt, k1);
        gemm2_conv_kernel<<<dim3(128, 4), 256, 0, stream>>>(k1, wc, bc, k2);
        gfeat_kernel<<<BATCH * CDIM / 4, 256, 0, stream>>>(feat, w_sp, g);
        clsfeat_kernel<<<NCLS, 256, 0, stream>>>(g, k2, b_sp, cls);
        cosface_kernel<<<BATCH, 256, 0, stream>>>(cls, w_cls, label, out);
    }
}